// Round 16
// baseline (759.668 us; speedup 1.0000x reference)
//
#include <hip/hip_runtime.h>

typedef unsigned short u16;
typedef unsigned int u32;
typedef __attribute__((ext_vector_type(4))) unsigned int u32x4;
typedef __attribute__((ext_vector_type(8))) short bf16x8;
typedef __attribute__((ext_vector_type(4))) float f32x4;

#define CIN 128
#define OC 128
#define NP 1024
#define KTOT 1152
#define NSTEP 18
#define BK 64
#define TILE_U16 8192
#define SAMP_U16 (NSTEP * TILE_U16)
#define XROW_U16 (36 * 128)
#define XSAMP_U16 (34 * XROW_U16)

typedef const u32 __attribute__((address_space(1)))* gptr_t;
typedef u32 __attribute__((address_space(3)))* lptr_t;

__device__ __forceinline__ u16 f2bf(float f) {
  unsigned b = __builtin_bit_cast(unsigned, f);
  b += 0x7fffu + ((b >> 16) & 1u);
  return (u16)(b >> 16);
}

// ---- prep body (r15-proven), REPEAT-able ----
template <int REPEAT>
__device__ __forceinline__ void prep_body(const float* __restrict__ w,
                                          const float* __restrict__ x,
                                          u16* __restrict__ wbf2,
                                          u16* __restrict__ xbf) {
  const int blk = blockIdx.x;
  const int t = threadIdx.x;
#pragma unroll 1
  for (int rep = 0; rep < REPEAT; ++rep) {
    if (blk < 4096) {                // wcvt
      __shared__ u16 lds[KTOT];
      const int i = blk >> 7, row = blk & 127;
      const float* src = w + (size_t)blk * KTOT;
#pragma unroll
      for (int e = 0; e < 9; ++e) {
        int idx = t + 128 * e;
        lds[idx] = f2bf(src[idx]);
      }
      __syncthreads();
      u16* dst = wbf2 + (size_t)i * SAMP_U16;
      const int rsw = row & 7;
#pragma unroll
      for (int e = 0; e < 9; ++e) {
        const int o = t + 128 * e;
        const int s = o >> 6;
        const int slotk = (o >> 3) & 7;
        const int ee = o & 7;
        dst[s * TILE_U16 + (row * 8 + (slotk ^ rsw)) * 8 + ee] = lds[t * 9 + e];
      }
      __syncthreads();
    } else if (blk < 5120) {         // xcvt
      __shared__ u16 rowbuf[XROW_U16];
      const int b = blk - 4096;
      const int i = b >> 5, y = b & 31;
      const int xx = t & 31;
      const int cg2 = t >> 5;
      const float* src = x + ((size_t)(i * CIN + cg2 * 32) * 32 + y) * 32 + xx;
      float v[32];
#pragma unroll
      for (int j = 0; j < 32; ++j) v[j] = src[(size_t)j * NP];
      u32 pk[16];
#pragma unroll
      for (int m = 0; m < 16; ++m)
        pk[m] = (u32)f2bf(v[2 * m]) | ((u32)f2bf(v[2 * m + 1]) << 16);
      const int col = xx + 1;
#pragma unroll
      for (int h = 0; h < 4; ++h) {
        const int sl = (cg2 * 4 + h) ^ (col & 7);
        *(u32x4*)(&rowbuf[col * 128 + sl * 8]) =
            (u32x4){pk[h * 4], pk[h * 4 + 1], pk[h * 4 + 2], pk[h * 4 + 3]};
      }
      if (t < 64) {
        const int hcs[4] = {0, 33, 34, 35};
        const int hc = hcs[t >> 4];
        *(u32x4*)(&rowbuf[hc * 128 + (t & 15) * 8]) = (u32x4){0, 0, 0, 0};
      }
      __syncthreads();
      u16* dst = xbf + (size_t)(i * 34 + (y + 1)) * XROW_U16;
#pragma unroll
      for (int j = 0; j < 4; ++j)
        *(u32x4*)(&dst[j * 1024 + t * 8]) = *(const u32x4*)(&rowbuf[j * 1024 + t * 8]);
      if (t < 64)
        *(u32x4*)(&dst[4096 + t * 8]) = *(const u32x4*)(&rowbuf[4096 + t * 8]);
      __syncthreads();
    } else {                         // halo rows
      const int b2 = blk - 5120;
      const int i = b2 >> 1;
      const int r = (b2 & 1) ? 33 : 0;
      u16* dst = xbf + (size_t)(i * 34 + r) * XROW_U16;
#pragma unroll
      for (int j = 0; j < 4; ++j)
        *(u32x4*)(&dst[j * 1024 + t * 8]) = (u32x4){0, 0, 0, 0};
      if (t < 64) *(u32x4*)(&dst[4096 + t * 8]) = (u32x4){0, 0, 0, 0};
    }
  }
}

__global__ void prep_kernel(const float* __restrict__ w, const float* __restrict__ x,
                            u16* __restrict__ wbf2, u16* __restrict__ xbf) {
  prep_body<1>(w, x, wbf2, xbf);
}
__global__ void prep_rep8(const float* __restrict__ w, const float* __restrict__ x,
                          u16* __restrict__ wbf2, u16* __restrict__ xbf) {
  prep_body<8>(w, x, wbf2, xbf);
}

// ---- conv body (r15-proven), ablatable ----
template <bool DSREAD, bool APIPE, int REPEAT, bool REAL>
__device__ __forceinline__ void conv_body(const u16* __restrict__ xbf,
                                          const u16* __restrict__ wbf2,
                                          const float* __restrict__ bias,
                                          float* __restrict__ outp) {
  __shared__ u16 Xs[6 * XROW_U16];
  __shared__ u16 Asw[TILE_U16];

  const int wg = (int)blockIdx.x;
  const int swz = (wg & 7) * 32 + (wg >> 3);
  const int i  = swz >> 3;
  const int pt = swz & 7;
  const int p0 = pt * 128;
  const int tid = (int)threadIdx.x;
  const int lane = tid & 63;
  const int wid = tid >> 6;
  const int wm = wid >> 1;
  const int wn = wid & 1;
  const int lcol = lane & 15;
  const int lhi  = lane >> 4;

  const u16* wt = wbf2 + (size_t)i * SAMP_U16;
  const u16* abase = wt + tid * 8;

  bf16x8 ar[4];
#define LOADA(step) do {                                          \
    const u16* _a = abase + (step) * TILE_U16;                    \
    _Pragma("unroll")                                             \
    for (int e = 0; e < 4; ++e)                                   \
      ar[e] = *(const bf16x8*)(_a + e * 2048);                    \
  } while (0)
#define STOREA() do {                                             \
    _Pragma("unroll")                                             \
    for (int e = 0; e < 4; ++e)                                   \
      *(bf16x8*)(&Asw[tid * 8 + e * 2048]) = ar[e];               \
  } while (0)

#pragma unroll 1
  for (int rep = 0; rep < REPEAT; ++rep) {
    __syncthreads();                 // Xs WAR across reps

    if constexpr (APIPE) LOADA(0);

    {
      const char* gsrc = (const char*)(xbf + (size_t)(i * 34 + 4 * pt) * XROW_U16);
      char* ldst = (char*)&Xs[0];
#pragma unroll
      for (int r = 0; r < 6; ++r) {
        const int rb = r * 9216;
#pragma unroll
        for (int q = 0; q < 2; ++q) {
          const int off = rb + q * 4096 + tid * 16;
          __builtin_amdgcn_global_load_lds((gptr_t)(gsrc + off),
                                           (lptr_t)(ldst + off), 16, 0, 0);
        }
        const int off4 = rb + 8192 + tid * 4;
        __builtin_amdgcn_global_load_lds((gptr_t)(gsrc + off4),
                                         (lptr_t)(ldst + off4), 4, 0, 0);
      }
    }

    f32x4 acc[4][4];
#pragma unroll
    for (int mi = 0; mi < 4; ++mi)
#pragma unroll
      for (int ni = 0; ni < 4; ++ni)
        acc[mi][ni] = (f32x4){0.f, 0.f, 0.f, 0.f};

    asm volatile("s_waitcnt vmcnt(0)" ::: "memory");
    if constexpr (APIPE) STOREA();
    __syncthreads();

#pragma unroll
    for (int step = 0; step < NSTEP; ++step) {
      const int rs = step >> 1;
      const int r3 = rs / 3;
      const int dy = r3 - 1;
      const int dx = (rs - r3 * 3) - 1;
      const int c0s = (step & 1) * 8;

      if constexpr (APIPE) {
        if (step + 1 < NSTEP) LOADA(step + 1);
      }

#pragma unroll
      for (int kkk = 0; kkk < 2; ++kkk) {
        bf16x8 af[4], bfr[4];
        if constexpr (DSREAD) {
#pragma unroll
          for (int mi = 0; mi < 4; ++mi) {
            const int row = wm * 64 + mi * 16 + lcol;
            const int slot = (kkk * 4 + lhi) ^ (row & 7);
            af[mi] = *(const bf16x8*)(&Asw[row * BK + slot * 8]);
          }
#pragma unroll
          for (int ni = 0; ni < 4; ++ni) {
            const int srow = wn * 2 + (ni >> 1) + 1 + dy;
            const int col  = (ni & 1) * 16 + lcol + 1 + dx;
            const int cslot = c0s + kkk * 4 + lhi;
            const int idx = ((srow * 36 + col) * 16 + (cslot ^ (col & 7))) * 8;
            bfr[ni] = *(const bf16x8*)(&Xs[idx]);
          }
        } else {
#pragma unroll
          for (int mi = 0; mi < 4; ++mi)
#pragma unroll
            for (int e = 0; e < 8; ++e) af[mi][e] = (short)(lane + e + kkk + mi);
#pragma unroll
          for (int ni = 0; ni < 4; ++ni)
#pragma unroll
            for (int e = 0; e < 8; ++e) bfr[ni][e] = (short)(lane - e + ni);
        }
        __builtin_amdgcn_s_setprio(1);
#pragma unroll
        for (int mi = 0; mi < 4; ++mi)
#pragma unroll
          for (int ni = 0; ni < 4; ++ni)
            acc[mi][ni] = __builtin_amdgcn_mfma_f32_16x16x32_bf16(
                af[mi], bfr[ni], acc[mi][ni], 0, 0, 0);
        __builtin_amdgcn_s_setprio(0);
      }

      if constexpr (APIPE) {
        if (step + 1 < NSTEP) {
          __syncthreads();
          STOREA();
          __syncthreads();
        }
      }
    }

    const int row0 = lhi * 4;
#pragma unroll
    for (int mi = 0; mi < 4; ++mi) {
      const int oc = wm * 64 + mi * 16 + row0;
#pragma unroll
      for (int jj = 0; jj < 4; ++jj) {
        float bv = 0.f;
        if constexpr (REAL) bv = bias[i * OC + oc + jj];
        float* orow = outp + ((size_t)i * OC + oc + jj) * NP;
#pragma unroll
        for (int ni = 0; ni < 4; ++ni) {
          const int pg = p0 + wn * 64 + ni * 16 + lcol;
          orow[pg] = acc[mi][ni][jj] + bv;
        }
      }
    }
  }
#undef LOADA
#undef STOREA
}

__global__ __launch_bounds__(256, 2) void conv_mfma(
    const u16* __restrict__ xbf, const u16* __restrict__ wbf2,
    const float* __restrict__ bias, float* __restrict__ out) {
  conv_body<true, true, 1, true>(xbf, wbf2, bias, out);
}
__global__ __launch_bounds__(256, 2) void conv_rep8(
    const u16* __restrict__ xbf, const u16* __restrict__ wbf2,
    const float* __restrict__ bias, float* __restrict__ out) {
  conv_body<true, true, 8, false>(xbf, wbf2, bias, out);
}
__global__ __launch_bounds__(256, 2) void conv_nods8(
    const u16* __restrict__ xbf, const u16* __restrict__ wbf2,
    const float* __restrict__ bias, float* __restrict__ out) {
  conv_body<false, true, 8, false>(xbf, wbf2, bias, out);
}
__global__ __launch_bounds__(256, 2) void conv_noa8(
    const u16* __restrict__ xbf, const u16* __restrict__ wbf2,
    const float* __restrict__ bias, float* __restrict__ out) {
  conv_body<true, false, 8, false>(xbf, wbf2, bias, out);
}

extern "C" void kernel_launch(void* const* d_in, const int* in_sizes, int n_in,
                              void* d_out, int out_size, void* d_ws, size_t ws_size,
                              hipStream_t stream) {
  const float* x    = (const float*)d_in[0];
  const float* w    = (const float*)d_in[1];
  const float* bias = (const float*)d_in[2];
  float* out = (float*)d_out;
  u16* wbf2 = (u16*)d_ws;                                 // 9.44 MB
  u16* xbf  = (u16*)((char*)d_ws + (16u << 20));          // 10.03 MB
  u16* dw   = (u16*)((char*)d_ws + (32u << 20));          // diag wbf2
  u16* dx   = (u16*)((char*)d_ws + (48u << 20));          // diag xbf
  float* dout = (float*)((char*)d_ws + (64u << 20));      // diag out

  // real path (identical to r15)
  prep_kernel<<<dim3(5184), dim3(128), 0, stream>>>(w, x, wbf2, xbf);
  conv_mfma<<<dim3(256), dim3(256), 0, stream>>>(xbf, wbf2, bias, out);
  // diagnostics (x8 each; will occupy rocprof top-5 above harness fills)
  prep_rep8<<<dim3(5184), dim3(128), 0, stream>>>(w, x, dw, dx);
  conv_rep8<<<dim3(256), dim3(256), 0, stream>>>(xbf, wbf2, bias, dout);
  conv_nods8<<<dim3(256), dim3(256), 0, stream>>>(xbf, wbf2, bias, dout);
  conv_noa8<<<dim3(256), dim3(256), 0, stream>>>(xbf, wbf2, bias, dout);
}